// Round 15
// baseline (162.980 us; speedup 1.0000x reference)
//
#include <hip/hip_runtime.h>

// Problem constants: B=4, De=Do=64, T=4, H=W=128, PATCH=7, R=3
#define ATTN_OFF 4194304                 // B*Do*H*W (mem region size in floats)
// packed attn ws: [b][G=256][t][13][64] float4  = 3,407,872 float4s
#define WS_F4_COUNT 3407872ull

// ---------------------------------------------------------------------------
// K1 v12 (FROZEN, wall-validated R14): 2-px window sharing, conflict-free
// b128 staging, XCD swizzle, early-issue/write-late pipeline + q prefetch.
// ---------------------------------------------------------------------------
__global__ __launch_bounds__(256, 1) void k1_corr(
    const float* __restrict__ m_in, const float* __restrict__ q_in,
    float* __restrict__ out)
{
  // bijective XCD swizzle (512 % 8 == 0)
  const int p = blockIdx.x + (blockIdx.y << 2) + (blockIdx.z << 5);
  const int l = ((p & 7) << 6) + (p >> 3);
  const int bx = l & 3, by = (l >> 2) & 7, bz = l >> 5;

  const int b = bz >> 2, t = bz & 3;
  const int h0 = by * 16, w0 = bx * 32;
  const int tid = threadIdx.x;
  const int tx = tid & 31, ty = tid >> 5;      // ty 0..7 -> px rows 2ty, 2ty+1

  __shared__ float m_s[22][42][4];      // 14,784 B
  float* const lds = &m_s[0][0][0];

  float acc0[49], acc1[49];
#pragma unroll
  for (int d = 0; d < 49; ++d) { acc0[d] = 0.f; acc1[d] = 0.f; }

  int goff0, goff1, goff2, goff3, loff0, loff1, loff2, loff3;
  float msk0, msk1, msk2, msk3;
#define K1_DECOMP(K, GO, LO, MS)                                           \
  {                                                                        \
    const int it = (tid + (K << 8)) < 836 ? (tid + (K << 8)) : 835;        \
    const int yy = it / 38;                                                \
    const int xx = it - 38 * yy;                                           \
    const int gy = h0 - 3 + yy, gx = w0 - 3 + xx;                          \
    MS = (((unsigned)gy < 128u) && ((unsigned)gx < 128u)) ? 1.f : 0.f;     \
    const int gyc = gy < 0 ? 0 : (gy > 127 ? 127 : gy);                    \
    const int gxc = gx < 0 ? 0 : (gx > 127 ? 127 : gx);                    \
    GO = (gyc << 7) + gxc;                                                 \
    LO = (yy * 42 + xx + 1) << 2;                                          \
  }
  K1_DECOMP(0, goff0, loff0, msk0)
  K1_DECOMP(1, goff1, loff1, msk1)
  K1_DECOMP(2, goff2, loff2, msk2)
  K1_DECOMP(3, goff3, loff3, msk3)
#undef K1_DECOMP
  const bool has3 = (tid < 68);

  const int qpix = ((h0 + 2 * ty) << 7) + w0 + tx;   // px0; px1 = +128

  float4 r0, r1, r2, r3;
  float qa[4], qb[4];
#define K1_LOAD(CC)                                                        \
  {                                                                        \
    const float* base = m_in + (((b * 64 + (CC) * 4) * 4 + t) << 14);      \
    const float* q;                                                        \
    q = base + goff0; r0.x = q[0]; r0.y = q[65536]; r0.z = q[131072]; r0.w = q[196608]; \
    q = base + goff1; r1.x = q[0]; r1.y = q[65536]; r1.z = q[131072]; r1.w = q[196608]; \
    q = base + goff2; r2.x = q[0]; r2.y = q[65536]; r2.z = q[131072]; r2.w = q[196608]; \
    if (has3) { q = base + goff3;                                          \
      r3.x = q[0]; r3.y = q[65536]; r3.z = q[131072]; r3.w = q[196608]; }  \
  }
  r3 = make_float4(0.f, 0.f, 0.f, 0.f);
  K1_LOAD(0)
#pragma unroll
  for (int k = 0; k < 4; ++k) {
    const float* qp = q_in + ((b * 64 + k) << 14) + qpix;
    qa[k] = qp[0];
    qb[k] = qp[128];
  }

#pragma unroll 1
  for (int cc = 0; cc < 16; ++cc) {     // 16 chunks x 4 channels
    __syncthreads();                    // prev phase's reads complete
    *(float4*)(lds + loff0) = make_float4(r0.x*msk0, r0.y*msk0, r0.z*msk0, r0.w*msk0);
    *(float4*)(lds + loff1) = make_float4(r1.x*msk1, r1.y*msk1, r1.z*msk1, r1.w*msk1);
    *(float4*)(lds + loff2) = make_float4(r2.x*msk2, r2.y*msk2, r2.z*msk2, r2.w*msk2);
    if (has3)
      *(float4*)(lds + loff3) = make_float4(r3.x*msk3, r3.y*msk3, r3.z*msk3, r3.w*msk3);
    __syncthreads();                    // writes visible

    float qan[4], qbn[4];
    if (cc < 15) {                      // issue next chunk's loads (no wait)
      K1_LOAD(cc + 1)
#pragma unroll
      for (int k = 0; k < 4; ++k) {
        const float* qp = q_in + ((b * 64 + (cc + 1) * 4 + k) << 14) + qpix;
        qan[k] = qp[0];
        qbn[k] = qp[128];
      }
    }

#pragma unroll
    for (int wr = 0; wr < 8; ++wr) {
      const float4* rowp = (const float4*)&m_s[2 * ty + wr][tx + 1][0];
#pragma unroll
      for (int dx = 0; dx < 7; ++dx) {
        const float4 mv = rowp[dx];
        if (wr < 7)
          acc0[wr * 7 + dx] += qa[0]*mv.x + qa[1]*mv.y + qa[2]*mv.z + qa[3]*mv.w;
        if (wr > 0)
          acc1[(wr - 1) * 7 + dx] += qb[0]*mv.x + qb[1]*mv.y + qb[2]*mv.z + qb[3]*mv.w;
      }
    }

    if (cc < 15) {
#pragma unroll
      for (int k = 0; k < 4; ++k) { qa[k] = qan[k]; qb[k] = qbn[k]; }
    }
  }
#undef K1_LOAD

  const int obase = ATTN_OFF + ((b * 196 + t) << 14)
                  + ((h0 + 2 * ty) << 7) + w0 + tx;
#pragma unroll
  for (int d = 0; d < 49; ++d) {
    out[obase +       ((d * 4) << 14)] = acc0[d];
    out[obase + 128 + ((d * 4) << 14)] = acc1[d];
  }
}

// ---------------------------------------------------------------------------
// K2 (FROZEN, near BW floor): softmax + packed-attn write into d_ws.
// Packed layout keyed to k3's wave tiling: G = (h>>1)*4 + (w>>5),
// lane = (h&1)*32 + (w&31); element (b,G,t,g,lane) at
// ((b*256+G)*4+t)*13*64 + g*64 + lane   (float4 units, d = 4g+j).
// ---------------------------------------------------------------------------
__global__ __launch_bounds__(256) void k2_softmax(
    float* __restrict__ out, const float* __restrict__ cst,
    float4* __restrict__ ws)
{
  const int tid = threadIdx.x;
  const int pl = tid & 63;             // pixel within block
  const int t  = tid >> 6;
  const int pix = blockIdx.x * 64 + pl;      // 65536 pixels total
  const int b = pix >> 14, hw = pix & 16383;
  float* base = out + ATTN_OFF + ((b * 196 + t) << 14) + hw;

  float v[49];
#pragma unroll
  for (int d = 0; d < 49; ++d) v[d] = base[(d * 4) << 14];

  float mx = -1e30f;
#pragma unroll
  for (int d = 0; d < 49; ++d) mx = fmaxf(mx, v[d]);

  __shared__ float red[4][64];
  red[t][pl] = mx;
  __syncthreads();
  float M = fmaxf(fmaxf(red[0][pl], red[1][pl]), fmaxf(red[2][pl], red[3][pl]));
  M = fmaxf(M, cst[0]);
  __syncthreads();

  float s = 0.f;
#pragma unroll
  for (int d = 0; d < 49; ++d) { v[d] = __expf(v[d] - M); s += v[d]; }
  red[t][pl] = s;
  __syncthreads();
  const float l = red[0][pl] + red[1][pl] + red[2][pl] + red[3][pl]
                + __expf(cst[0] - M);
  const float inv = 1.f / l;
#pragma unroll
  for (int d = 0; d < 49; ++d) {
    const float r = v[d] * inv;
    base[(d * 4) << 14] = r;           // reference-layout output (validated)
    v[d] = r;
  }

  if (ws) {
    const int h = hw >> 7, wc = hw & 127;
    const int G    = ((h >> 1) << 2) + (wc >> 5);
    const int lane = ((h & 1) << 5) + (wc & 31);
    float4* dst = ws + (size_t)(((b * 256 + G) * 4 + t) * 13) * 64 + lane;
#pragma unroll
    for (int g = 0; g < 13; ++g) {
      float4 p;
      p.x = v[g * 4];
      p.y = (g < 12) ? v[g * 4 + 1] : 0.f;
      p.z = (g < 12) ? v[g * 4 + 2] : 0.f;
      p.w = (g < 12) ? v[g * 4 + 3] : 0.f;
      dst[g * 64] = p;
    }
  }
}

// ---------------------------------------------------------------------------
// K3 v7 (packed-ws): 2-vertical-px window sharing (k1-v12 mechanism).
//  - R14 model: v6 (1 px/thread) is AT its LDS floor (98 b128/thr/t ->
//    12,544 wave-insts/CU ~= 63 us). 2-px sharing: 56 b128/t serve 2 px
//    -> 7,168/CU ~= 36 us floor.
//  - blocks own 4 channels (1 quad) x 32x16 tile: LDS [22][42][4] =
//    14,784 B (avoids R3's 59 KB and R6/R10's 29.5/18.9 KB occupancy
//    cliffs). grid (4,8,64) = 2048 blocks, cq-fastest bijective swizzle:
//    16 cq-siblings of a tile run consecutively on one XCD -> attn L2 hits.
//  - attn unpacked to 98 statically-indexed scalars (R3 structure; its
//    failure was occupancy, not the unpack); t+1 attn issued AFTER compute
//    t so the wait hides under next iter's barrier+write. m_out staged with
//    k1-v12's early-issue 4-item pipeline.
//  - d ascending, t outer, per-channel order unchanged -> numerics identical.
// ---------------------------------------------------------------------------
__global__ __launch_bounds__(256, 1) void k3_read_ws(
    const float* __restrict__ m_out, float* __restrict__ out,
    const float4* __restrict__ ws)
{
  // bijective XCD swizzle (2048 % 8 == 0), cq fastest within each XCD
  const int p = blockIdx.x + (blockIdx.y << 2) + (blockIdx.z << 5);
  const int l = ((p & 7) << 8) + (p >> 3);
  const int cq = l & 15;                     // 16 groups x 4 channels
  const int tile = l >> 4;                   // 0..127
  const int bx = tile & 3, by = (tile >> 2) & 7, b = tile >> 5;

  const int h0 = by * 16, w0 = bx * 32;
  const int tid = threadIdx.x;
  const int tx = tid & 31, ty = tid >> 5;    // px rows 2ty, 2ty+1
  const int G = ((h0 >> 1) + ty) * 4 + bx;   // shared by both pixels

  __shared__ float m_s[22][42][4];    // 14,784 B
  float* const lds = &m_s[0][0][0];

  float acc0[4], acc1[4];
#pragma unroll
  for (int i = 0; i < 4; ++i) { acc0[i] = 0.f; acc1[i] = 0.f; }

  int goff0, goff1, goff2, goff3, loff0, loff1, loff2, loff3;
  float msk0, msk1, msk2, msk3;
#define K3_DECOMP(K, GO, LO, MS)                                           \
  {                                                                        \
    const int it = (tid + (K << 8)) < 836 ? (tid + (K << 8)) : 835;        \
    const int yy = it / 38;                                                \
    const int xx = it - 38 * yy;                                           \
    const int gy = h0 - 3 + yy, gx = w0 - 3 + xx;                          \
    MS = (((unsigned)gy < 128u) && ((unsigned)gx < 128u)) ? 1.f : 0.f;     \
    const int gyc = gy < 0 ? 0 : (gy > 127 ? 127 : gy);                    \
    const int gxc = gx < 0 ? 0 : (gx > 127 ? 127 : gx);                    \
    GO = (gyc << 7) + gxc;                                                 \
    LO = (yy * 42 + xx + 1) << 2;                                          \
  }
  K3_DECOMP(0, goff0, loff0, msk0)
  K3_DECOMP(1, goff1, loff1, msk1)
  K3_DECOMP(2, goff2, loff2, msk2)
  K3_DECOMP(3, goff3, loff3, msk3)
#undef K3_DECOMP
  const bool has3 = (tid < 68);

  float4 r0, r1, r2, r3;
#define K3_LOAD(T)                                                         \
  {                                                                        \
    const float* base = m_out + (((b * 64 + cq * 4) * 4 + (T)) << 14);     \
    const float* q;                                                        \
    q = base + goff0; r0.x = q[0]; r0.y = q[65536]; r0.z = q[131072]; r0.w = q[196608]; \
    q = base + goff1; r1.x = q[0]; r1.y = q[65536]; r1.z = q[131072]; r1.w = q[196608]; \
    q = base + goff2; r2.x = q[0]; r2.y = q[65536]; r2.z = q[131072]; r2.w = q[196608]; \
    if (has3) { q = base + goff3;                                          \
      r3.x = q[0]; r3.y = q[65536]; r3.z = q[131072]; r3.w = q[196608]; }  \
  }

  // attn unpack for t: 26 coalesced f4 -> 98 statically-indexed scalars
  float av0[49], av1[49];
#define K3_ATTN(T)                                                         \
  {                                                                        \
    const float4* ap = ws + (size_t)(((b * 256 + G) * 4 + (T)) * 13) * 64; \
    _Pragma("unroll")                                                      \
    for (int g = 0; g < 13; ++g) {                                         \
      const float4 a0 = ap[g * 64 + tx];                                   \
      const float4 a1 = ap[g * 64 + 32 + tx];                              \
      av0[g * 4] = a0.x;                                                   \
      av1[g * 4] = a1.x;                                                   \
      if (g < 12) {                                                        \
        av0[g * 4 + 1] = a0.y; av0[g * 4 + 2] = a0.z; av0[g * 4 + 3] = a0.w; \
        av1[g * 4 + 1] = a1.y; av1[g * 4 + 2] = a1.z; av1[g * 4 + 3] = a1.w; \
      }                                                                    \
    }                                                                      \
  }

  r3 = make_float4(0.f, 0.f, 0.f, 0.f);
  K3_LOAD(0)
  K3_ATTN(0)

#pragma unroll 1
  for (int t = 0; t < 4; ++t) {
    __syncthreads();                   // prev phase's reads complete
    *(float4*)(lds + loff0) = make_float4(r0.x*msk0, r0.y*msk0, r0.z*msk0, r0.w*msk0);
    *(float4*)(lds + loff1) = make_float4(r1.x*msk1, r1.y*msk1, r1.z*msk1, r1.w*msk1);
    *(float4*)(lds + loff2) = make_float4(r2.x*msk2, r2.y*msk2, r2.z*msk2, r2.w*msk2);
    if (has3)
      *(float4*)(lds + loff3) = make_float4(r3.x*msk3, r3.y*msk3, r3.z*msk3, r3.w*msk3);
    __syncthreads();                   // writes visible

    if (t < 3) K3_LOAD(t + 1)          // issue next t's m_out loads (no wait)

    // compute: shared 8-row window feeds both pixels
#pragma unroll
    for (int wr = 0; wr < 8; ++wr) {
      const float4* rowp = (const float4*)&m_s[2 * ty + wr][tx + 1][0];
#pragma unroll
      for (int dx = 0; dx < 7; ++dx) {
        const float4 mv = rowp[dx];
        if (wr < 7) {
          const float a = av0[wr * 7 + dx];
          acc0[0] += a * mv.x; acc0[1] += a * mv.y;
          acc0[2] += a * mv.z; acc0[3] += a * mv.w;
        }
        if (wr > 0) {
          const float a = av1[(wr - 1) * 7 + dx];
          acc1[0] += a * mv.x; acc1[1] += a * mv.y;
          acc1[2] += a * mv.z; acc1[3] += a * mv.w;
        }
      }
    }

    if (t < 3) K3_ATTN(t + 1)          // issue next t's attn (waited next iter)
  }
#undef K3_LOAD
#undef K3_ATTN

  const int ob = ((b * 64 + cq * 4) << 14) + ((h0 + 2 * ty) << 7) + w0 + tx;
#pragma unroll
  for (int k = 0; k < 4; ++k) {
    out[ob +       (k << 14)] = acc0[k];
    out[ob + 128 + (k << 14)] = acc1[k];
  }
}

// ---------------------------------------------------------------------------
// K3 fallback (unchanged) — used only if ws_size is too small.
// ---------------------------------------------------------------------------
__global__ __launch_bounds__(256) void k3_read_fb(
    const float* __restrict__ m_out, float* __restrict__ out)
{
  const int b = blockIdx.z >> 2, cq = blockIdx.z & 3;
  const int h0 = blockIdx.y * 8, w0 = blockIdx.x * 32;
  const int tid = threadIdx.x;
  const int tx = tid & 31, ty = tid >> 5;
  const int h = h0 + ty, w = w0 + tx;

  __shared__ float m_s[4][14][38][4];
  const float* __restrict__ attn = out + ATTN_OFF;

  float acc[16];
#pragma unroll
  for (int i = 0; i < 16; ++i) acc[i] = 0.f;

#pragma unroll 1
  for (int t = 0; t < 4; ++t) {
    float a[49];
#pragma unroll
    for (int d = 0; d < 49; ++d)
      a[d] = attn[((b * 196 + d * 4 + t) << 14) + (h << 7) + w];

    __syncthreads();
    for (int e = tid; e < 8512; e += 256) {
      int c16 = e / 532; int rem = e - c16 * 532;
      int y = rem / 38;  int x = rem - y * 38;
      int gy = h0 - 3 + y, gx = w0 - 3 + x;
      float v = 0.f;
      if (gy >= 0 && gy < 128 && gx >= 0 && gx < 128)
        v = m_out[(((b * 64 + cq * 16 + c16) * 4 + t) << 14) + (gy << 7) + gx];
      m_s[c16 >> 2][y][x][c16 & 3] = v;
    }
    __syncthreads();

#pragma unroll
    for (int dy = 0; dy < 7; ++dy)
#pragma unroll
      for (int dx = 0; dx < 7; ++dx) {
        const float av = a[dy * 7 + dx];
#pragma unroll
        for (int q = 0; q < 4; ++q) {
          const float4 mv = *(const float4*)&m_s[q][ty + dy][tx + dx][0];
          acc[q * 4 + 0] += av * mv.x;
          acc[q * 4 + 1] += av * mv.y;
          acc[q * 4 + 2] += av * mv.z;
          acc[q * 4 + 3] += av * mv.w;
        }
      }
  }

#pragma unroll
  for (int q = 0; q < 4; ++q)
#pragma unroll
    for (int k = 0; k < 4; ++k)
      out[((b * 64 + cq * 16 + q * 4 + k) << 14) + (h << 7) + w] = acc[q * 4 + k];
}

extern "C" void kernel_launch(void* const* d_in, const int* in_sizes, int n_in,
                              void* d_out, int out_size, void* d_ws, size_t ws_size,
                              hipStream_t stream) {
  const float* m_in  = (const float*)d_in[0];
  const float* m_out = (const float*)d_in[1];
  const float* q_in  = (const float*)d_in[2];
  const float* cst   = (const float*)d_in[3];
  float* out = (float*)d_out;

  const bool use_ws = (ws_size >= WS_F4_COUNT * 16ull) && d_ws != nullptr;
  float4* ws = use_ws ? (float4*)d_ws : nullptr;

  k1_corr<<<dim3(4, 8, 16), dim3(256), 0, stream>>>(m_in, q_in, out);
  k2_softmax<<<dim3(1024), dim3(256), 0, stream>>>(out, cst, ws);
  if (use_ws)
    k3_read_ws<<<dim3(4, 8, 64), dim3(256), 0, stream>>>(m_out, out, ws);
  else
    k3_read_fb<<<dim3(4, 16, 16), dim3(256), 0, stream>>>(m_out, out);
}

// Round 16
// 127.336 us; speedup vs baseline: 1.2799x; 1.2799x over previous
//
#include <hip/hip_runtime.h>

// Problem constants: B=4, De=Do=64, T=4, H=W=128, PATCH=7, R=3
#define ATTN_OFF 4194304                 // B*Do*H*W (mem region size in floats)
// packed attn ws: [b][G=256][t][13][64] float4  = 3,407,872 float4s
#define WS_F4_COUNT 3407872ull

// ---------------------------------------------------------------------------
// K1 v12 (FROZEN, wall-validated R14): 2-px window sharing, conflict-free
// b128 staging, XCD swizzle, early-issue/write-late pipeline + q prefetch.
// ---------------------------------------------------------------------------
__global__ __launch_bounds__(256, 1) void k1_corr(
    const float* __restrict__ m_in, const float* __restrict__ q_in,
    float* __restrict__ out)
{
  // bijective XCD swizzle (512 % 8 == 0)
  const int p = blockIdx.x + (blockIdx.y << 2) + (blockIdx.z << 5);
  const int l = ((p & 7) << 6) + (p >> 3);
  const int bx = l & 3, by = (l >> 2) & 7, bz = l >> 5;

  const int b = bz >> 2, t = bz & 3;
  const int h0 = by * 16, w0 = bx * 32;
  const int tid = threadIdx.x;
  const int tx = tid & 31, ty = tid >> 5;      // ty 0..7 -> px rows 2ty, 2ty+1

  __shared__ float m_s[22][42][4];      // 14,784 B
  float* const lds = &m_s[0][0][0];

  float acc0[49], acc1[49];
#pragma unroll
  for (int d = 0; d < 49; ++d) { acc0[d] = 0.f; acc1[d] = 0.f; }

  int goff0, goff1, goff2, goff3, loff0, loff1, loff2, loff3;
  float msk0, msk1, msk2, msk3;
#define K1_DECOMP(K, GO, LO, MS)                                           \
  {                                                                        \
    const int it = (tid + (K << 8)) < 836 ? (tid + (K << 8)) : 835;        \
    const int yy = it / 38;                                                \
    const int xx = it - 38 * yy;                                           \
    const int gy = h0 - 3 + yy, gx = w0 - 3 + xx;                          \
    MS = (((unsigned)gy < 128u) && ((unsigned)gx < 128u)) ? 1.f : 0.f;     \
    const int gyc = gy < 0 ? 0 : (gy > 127 ? 127 : gy);                    \
    const int gxc = gx < 0 ? 0 : (gx > 127 ? 127 : gx);                    \
    GO = (gyc << 7) + gxc;                                                 \
    LO = (yy * 42 + xx + 1) << 2;                                          \
  }
  K1_DECOMP(0, goff0, loff0, msk0)
  K1_DECOMP(1, goff1, loff1, msk1)
  K1_DECOMP(2, goff2, loff2, msk2)
  K1_DECOMP(3, goff3, loff3, msk3)
#undef K1_DECOMP
  const bool has3 = (tid < 68);

  const int qpix = ((h0 + 2 * ty) << 7) + w0 + tx;   // px0; px1 = +128

  float4 r0, r1, r2, r3;
  float qa[4], qb[4];
#define K1_LOAD(CC)                                                        \
  {                                                                        \
    const float* base = m_in + (((b * 64 + (CC) * 4) * 4 + t) << 14);      \
    const float* q;                                                        \
    q = base + goff0; r0.x = q[0]; r0.y = q[65536]; r0.z = q[131072]; r0.w = q[196608]; \
    q = base + goff1; r1.x = q[0]; r1.y = q[65536]; r1.z = q[131072]; r1.w = q[196608]; \
    q = base + goff2; r2.x = q[0]; r2.y = q[65536]; r2.z = q[131072]; r2.w = q[196608]; \
    if (has3) { q = base + goff3;                                          \
      r3.x = q[0]; r3.y = q[65536]; r3.z = q[131072]; r3.w = q[196608]; }  \
  }
  r3 = make_float4(0.f, 0.f, 0.f, 0.f);
  K1_LOAD(0)
#pragma unroll
  for (int k = 0; k < 4; ++k) {
    const float* qp = q_in + ((b * 64 + k) << 14) + qpix;
    qa[k] = qp[0];
    qb[k] = qp[128];
  }

#pragma unroll 1
  for (int cc = 0; cc < 16; ++cc) {     // 16 chunks x 4 channels
    __syncthreads();                    // prev phase's reads complete
    *(float4*)(lds + loff0) = make_float4(r0.x*msk0, r0.y*msk0, r0.z*msk0, r0.w*msk0);
    *(float4*)(lds + loff1) = make_float4(r1.x*msk1, r1.y*msk1, r1.z*msk1, r1.w*msk1);
    *(float4*)(lds + loff2) = make_float4(r2.x*msk2, r2.y*msk2, r2.z*msk2, r2.w*msk2);
    if (has3)
      *(float4*)(lds + loff3) = make_float4(r3.x*msk3, r3.y*msk3, r3.z*msk3, r3.w*msk3);
    __syncthreads();                    // writes visible

    float qan[4], qbn[4];
    if (cc < 15) {                      // issue next chunk's loads (no wait)
      K1_LOAD(cc + 1)
#pragma unroll
      for (int k = 0; k < 4; ++k) {
        const float* qp = q_in + ((b * 64 + (cc + 1) * 4 + k) << 14) + qpix;
        qan[k] = qp[0];
        qbn[k] = qp[128];
      }
    }

#pragma unroll
    for (int wr = 0; wr < 8; ++wr) {
      const float4* rowp = (const float4*)&m_s[2 * ty + wr][tx + 1][0];
#pragma unroll
      for (int dx = 0; dx < 7; ++dx) {
        const float4 mv = rowp[dx];
        if (wr < 7)
          acc0[wr * 7 + dx] += qa[0]*mv.x + qa[1]*mv.y + qa[2]*mv.z + qa[3]*mv.w;
        if (wr > 0)
          acc1[(wr - 1) * 7 + dx] += qb[0]*mv.x + qb[1]*mv.y + qb[2]*mv.z + qb[3]*mv.w;
      }
    }

    if (cc < 15) {
#pragma unroll
      for (int k = 0; k < 4; ++k) { qa[k] = qan[k]; qb[k] = qbn[k]; }
    }
  }
#undef K1_LOAD

  const int obase = ATTN_OFF + ((b * 196 + t) << 14)
                  + ((h0 + 2 * ty) << 7) + w0 + tx;
#pragma unroll
  for (int d = 0; d < 49; ++d) {
    out[obase +       ((d * 4) << 14)] = acc0[d];
    out[obase + 128 + ((d * 4) << 14)] = acc1[d];
  }
}

// ---------------------------------------------------------------------------
// K2 (FROZEN, near BW floor): softmax + packed-attn write into d_ws.
// Packed layout keyed to k3's wave tiling: G = (h>>1)*4 + (w>>5),
// lane = (h&1)*32 + (w&31); element (b,G,t,g,lane) at
// ((b*256+G)*4+t)*13*64 + g*64 + lane   (float4 units, d = 4g+j).
// ---------------------------------------------------------------------------
__global__ __launch_bounds__(256) void k2_softmax(
    float* __restrict__ out, const float* __restrict__ cst,
    float4* __restrict__ ws)
{
  const int tid = threadIdx.x;
  const int pl = tid & 63;             // pixel within block
  const int t  = tid >> 6;
  const int pix = blockIdx.x * 64 + pl;      // 65536 pixels total
  const int b = pix >> 14, hw = pix & 16383;
  float* base = out + ATTN_OFF + ((b * 196 + t) << 14) + hw;

  float v[49];
#pragma unroll
  for (int d = 0; d < 49; ++d) v[d] = base[(d * 4) << 14];

  float mx = -1e30f;
#pragma unroll
  for (int d = 0; d < 49; ++d) mx = fmaxf(mx, v[d]);

  __shared__ float red[4][64];
  red[t][pl] = mx;
  __syncthreads();
  float M = fmaxf(fmaxf(red[0][pl], red[1][pl]), fmaxf(red[2][pl], red[3][pl]));
  M = fmaxf(M, cst[0]);
  __syncthreads();

  float s = 0.f;
#pragma unroll
  for (int d = 0; d < 49; ++d) { v[d] = __expf(v[d] - M); s += v[d]; }
  red[t][pl] = s;
  __syncthreads();
  const float l = red[0][pl] + red[1][pl] + red[2][pl] + red[3][pl]
                + __expf(cst[0] - M);
  const float inv = 1.f / l;
#pragma unroll
  for (int d = 0; d < 49; ++d) {
    const float r = v[d] * inv;
    base[(d * 4) << 14] = r;           // reference-layout output (validated)
    v[d] = r;
  }

  if (ws) {
    const int h = hw >> 7, wc = hw & 127;
    const int G    = ((h >> 1) << 2) + (wc >> 5);
    const int lane = ((h & 1) << 5) + (wc & 31);
    float4* dst = ws + (size_t)(((b * 256 + G) * 4 + t) * 13) * 64 + lane;
#pragma unroll
    for (int g = 0; g < 13; ++g) {
      float4 p;
      p.x = v[g * 4];
      p.y = (g < 12) ? v[g * 4 + 1] : 0.f;
      p.z = (g < 12) ? v[g * 4 + 2] : 0.f;
      p.w = (g < 12) ? v[g * 4 + 3] : 0.f;
      dst[g * 64] = p;
    }
  }
}

// ---------------------------------------------------------------------------
// K3 v8 (packed-ws): 2-px window sharing + ROLLING 2-row attn stream.
//  - v7's skeleton (swizzle, staging, FMA order -> numerics validated) but
//    the 98-scalar attn hold (VGPR 248, occupancy 10.8% in R15) is replaced
//    by a rolling stream: at window row wr only px0-row-wr and px1-row-(wr-1)
//    are live (7+7 scalars, double-buffered = 28 regs).
//  - rows loaded as scalar dwords from packed ws (compile-time offsets,
//    L2-resident: 16 cq-siblings share 64 KB attn via cq-fastest swizzle),
//    issued one row ahead inside each unrolled wr region.
//  - sched_barrier(0) at each wr region top prevents the scheduler from
//    re-hoisting all loads into a v7-style register balloon.
//  - est ~90 live VGPR -> 4-5 waves/SIMD.
// ---------------------------------------------------------------------------
__global__ __launch_bounds__(256, 2) void k3_read_ws(
    const float* __restrict__ m_out, float* __restrict__ out,
    const float4* __restrict__ ws)
{
  // bijective XCD swizzle (2048 % 8 == 0), cq fastest within each XCD
  const int p = blockIdx.x + (blockIdx.y << 2) + (blockIdx.z << 5);
  const int l = ((p & 7) << 8) + (p >> 3);
  const int cq = l & 15;                     // 16 groups x 4 channels
  const int tile = l >> 4;                   // 0..127
  const int bx = tile & 3, by = (tile >> 2) & 7, b = tile >> 5;

  const int h0 = by * 16, w0 = bx * 32;
  const int tid = threadIdx.x;
  const int tx = tid & 31, ty = tid >> 5;    // px rows 2ty, 2ty+1
  const int G = ((h0 >> 1) + ty) * 4 + bx;   // shared by both pixels

  __shared__ float m_s[22][42][4];    // 14,784 B
  float* const lds = &m_s[0][0][0];

  float acc0[4], acc1[4];
#pragma unroll
  for (int i = 0; i < 4; ++i) { acc0[i] = 0.f; acc1[i] = 0.f; }

  int goff0, goff1, goff2, goff3, loff0, loff1, loff2, loff3;
  float msk0, msk1, msk2, msk3;
#define K3_DECOMP(K, GO, LO, MS)                                           \
  {                                                                        \
    const int it = (tid + (K << 8)) < 836 ? (tid + (K << 8)) : 835;        \
    const int yy = it / 38;                                                \
    const int xx = it - 38 * yy;                                           \
    const int gy = h0 - 3 + yy, gx = w0 - 3 + xx;                          \
    MS = (((unsigned)gy < 128u) && ((unsigned)gx < 128u)) ? 1.f : 0.f;     \
    const int gyc = gy < 0 ? 0 : (gy > 127 ? 127 : gy);                    \
    const int gxc = gx < 0 ? 0 : (gx > 127 ? 127 : gx);                    \
    GO = (gyc << 7) + gxc;                                                 \
    LO = (yy * 42 + xx + 1) << 2;                                          \
  }
  K3_DECOMP(0, goff0, loff0, msk0)
  K3_DECOMP(1, goff1, loff1, msk1)
  K3_DECOMP(2, goff2, loff2, msk2)
  K3_DECOMP(3, goff3, loff3, msk3)
#undef K3_DECOMP
  const bool has3 = (tid < 68);

  float4 r0, r1, r2, r3;
#define K3_LOAD(T)                                                         \
  {                                                                        \
    const float* base = m_out + (((b * 64 + cq * 4) * 4 + (T)) << 14);     \
    const float* q;                                                        \
    q = base + goff0; r0.x = q[0]; r0.y = q[65536]; r0.z = q[131072]; r0.w = q[196608]; \
    q = base + goff1; r1.x = q[0]; r1.y = q[65536]; r1.z = q[131072]; r1.w = q[196608]; \
    q = base + goff2; r2.x = q[0]; r2.y = q[65536]; r2.z = q[131072]; r2.w = q[196608]; \
    if (has3) { q = base + goff3;                                          \
      r3.x = q[0]; r3.y = q[65536]; r3.z = q[131072]; r3.w = q[196608]; }  \
  }
  r3 = make_float4(0.f, 0.f, 0.f, 0.f);
  K3_LOAD(0)

  float a0c[7], a1c[7];

#pragma unroll 1
  for (int t = 0; t < 4; ++t) {
    const float* awt = (const float*)(ws
        + (size_t)(((b * 256 + G) * 4 + t) * 13) * 64);
    const float* ab0 = awt + (tx << 2);          // px0 lane
    const float* ab1 = awt + (tx << 2) + 128;    // px1 lane (+32 f4 lanes)

    // preload px0 row 0 for this t (overlaps the barrier wait)
#pragma unroll
    for (int dxx = 0; dxx < 7; ++dxx)
      a0c[dxx] = ab0[((dxx >> 2) << 8) + (dxx & 3)];   // row0: d = dxx

    __syncthreads();                   // prev phase's reads complete
    *(float4*)(lds + loff0) = make_float4(r0.x*msk0, r0.y*msk0, r0.z*msk0, r0.w*msk0);
    *(float4*)(lds + loff1) = make_float4(r1.x*msk1, r1.y*msk1, r1.z*msk1, r1.w*msk1);
    *(float4*)(lds + loff2) = make_float4(r2.x*msk2, r2.y*msk2, r2.z*msk2, r2.w*msk2);
    if (has3)
      *(float4*)(lds + loff3) = make_float4(r3.x*msk3, r3.y*msk3, r3.z*msk3, r3.w*msk3);
    __syncthreads();                   // writes visible

    if (t < 3) K3_LOAD(t + 1)          // issue next t's m_out loads (no wait)

#pragma unroll
    for (int wr = 0; wr < 8; ++wr) {
      __builtin_amdgcn_sched_barrier(0);   // keep each wr region's loads local
      float a0n[7], a1n[7];
      if (wr < 6) {                        // px0 row wr+1 (used next region)
#pragma unroll
        for (int dxx = 0; dxx < 7; ++dxx) {
          const int d = (wr + 1) * 7 + dxx;
          a0n[dxx] = ab0[((d >> 2) << 8) + (d & 3)];
        }
      }
      if (wr < 7) {                        // px1 row wr (used next region)
#pragma unroll
        for (int dxx = 0; dxx < 7; ++dxx) {
          const int d = wr * 7 + dxx;
          a1n[dxx] = ab1[((d >> 2) << 8) + (d & 3)];
        }
      }

      const float4* rowp = (const float4*)&m_s[2 * ty + wr][tx + 1][0];
#pragma unroll
      for (int dx = 0; dx < 7; ++dx) {
        const float4 mv = rowp[dx];
        if (wr < 7) {
          const float a = a0c[dx];
          acc0[0] += a * mv.x; acc0[1] += a * mv.y;
          acc0[2] += a * mv.z; acc0[3] += a * mv.w;
        }
        if (wr > 0) {
          const float a = a1c[dx];
          acc1[0] += a * mv.x; acc1[1] += a * mv.y;
          acc1[2] += a * mv.z; acc1[3] += a * mv.w;
        }
      }

      if (wr < 6) {
#pragma unroll
        for (int dxx = 0; dxx < 7; ++dxx) a0c[dxx] = a0n[dxx];
      }
      if (wr < 7) {
#pragma unroll
        for (int dxx = 0; dxx < 7; ++dxx) a1c[dxx] = a1n[dxx];
      }
    }
  }
#undef K3_LOAD

  const int ob = ((b * 64 + cq * 4) << 14) + ((h0 + 2 * ty) << 7) + w0 + tx;
#pragma unroll
  for (int k = 0; k < 4; ++k) {
    out[ob +       (k << 14)] = acc0[k];
    out[ob + 128 + (k << 14)] = acc1[k];
  }
}

// ---------------------------------------------------------------------------
// K3 fallback (unchanged) — used only if ws_size is too small.
// ---------------------------------------------------------------------------
__global__ __launch_bounds__(256) void k3_read_fb(
    const float* __restrict__ m_out, float* __restrict__ out)
{
  const int b = blockIdx.z >> 2, cq = blockIdx.z & 3;
  const int h0 = blockIdx.y * 8, w0 = blockIdx.x * 32;
  const int tid = threadIdx.x;
  const int tx = tid & 31, ty = tid >> 5;
  const int h = h0 + ty, w = w0 + tx;

  __shared__ float m_s[4][14][38][4];
  const float* __restrict__ attn = out + ATTN_OFF;

  float acc[16];
#pragma unroll
  for (int i = 0; i < 16; ++i) acc[i] = 0.f;

#pragma unroll 1
  for (int t = 0; t < 4; ++t) {
    float a[49];
#pragma unroll
    for (int d = 0; d < 49; ++d)
      a[d] = attn[((b * 196 + d * 4 + t) << 14) + (h << 7) + w];

    __syncthreads();
    for (int e = tid; e < 8512; e += 256) {
      int c16 = e / 532; int rem = e - c16 * 532;
      int y = rem / 38;  int x = rem - y * 38;
      int gy = h0 - 3 + y, gx = w0 - 3 + x;
      float v = 0.f;
      if (gy >= 0 && gy < 128 && gx >= 0 && gx < 128)
        v = m_out[(((b * 64 + cq * 16 + c16) * 4 + t) << 14) + (gy << 7) + gx];
      m_s[c16 >> 2][y][x][c16 & 3] = v;
    }
    __syncthreads();

#pragma unroll
    for (int dy = 0; dy < 7; ++dy)
#pragma unroll
      for (int dx = 0; dx < 7; ++dx) {
        const float av = a[dy * 7 + dx];
#pragma unroll
        for (int q = 0; q < 4; ++q) {
          const float4 mv = *(const float4*)&m_s[q][ty + dy][tx + dx][0];
          acc[q * 4 + 0] += av * mv.x;
          acc[q * 4 + 1] += av * mv.y;
          acc[q * 4 + 2] += av * mv.z;
          acc[q * 4 + 3] += av * mv.w;
        }
      }
  }

#pragma unroll
  for (int q = 0; q < 4; ++q)
#pragma unroll
    for (int k = 0; k < 4; ++k)
      out[((b * 64 + cq * 16 + q * 4 + k) << 14) + (h << 7) + w] = acc[q * 4 + k];
}

extern "C" void kernel_launch(void* const* d_in, const int* in_sizes, int n_in,
                              void* d_out, int out_size, void* d_ws, size_t ws_size,
                              hipStream_t stream) {
  const float* m_in  = (const float*)d_in[0];
  const float* m_out = (const float*)d_in[1];
  const float* q_in  = (const float*)d_in[2];
  const float* cst   = (const float*)d_in[3];
  float* out = (float*)d_out;

  const bool use_ws = (ws_size >= WS_F4_COUNT * 16ull) && d_ws != nullptr;
  float4* ws = use_ws ? (float4*)d_ws : nullptr;

  k1_corr<<<dim3(4, 8, 16), dim3(256), 0, stream>>>(m_in, q_in, out);
  k2_softmax<<<dim3(1024), dim3(256), 0, stream>>>(out, cst, ws);
  if (use_ws)
    k3_read_ws<<<dim3(4, 8, 64), dim3(256), 0, stream>>>(m_out, out, ws);
  else
    k3_read_fb<<<dim3(4, 16, 16), dim3(256), 0, stream>>>(m_out, out);
}

// Round 17
// 125.376 us; speedup vs baseline: 1.2999x; 1.0156x over previous
//
#include <hip/hip_runtime.h>

// Problem constants: B=4, De=Do=64, T=4, H=W=128, PATCH=7, R=3
#define ATTN_OFF 4194304                 // B*Do*H*W (mem region size in floats)
// packed attn ws: [b][G=256][t][13][64] float4  = 3,407,872 float4s
#define WS_F4_COUNT 3407872ull

// ---------------------------------------------------------------------------
// K1 v12 (FROZEN, wall-validated R14): 2-px window sharing, conflict-free
// b128 staging, XCD swizzle, early-issue/write-late pipeline + q prefetch.
// ---------------------------------------------------------------------------
__global__ __launch_bounds__(256, 1) void k1_corr(
    const float* __restrict__ m_in, const float* __restrict__ q_in,
    float* __restrict__ out)
{
  // bijective XCD swizzle (512 % 8 == 0)
  const int p = blockIdx.x + (blockIdx.y << 2) + (blockIdx.z << 5);
  const int l = ((p & 7) << 6) + (p >> 3);
  const int bx = l & 3, by = (l >> 2) & 7, bz = l >> 5;

  const int b = bz >> 2, t = bz & 3;
  const int h0 = by * 16, w0 = bx * 32;
  const int tid = threadIdx.x;
  const int tx = tid & 31, ty = tid >> 5;      // ty 0..7 -> px rows 2ty, 2ty+1

  __shared__ float m_s[22][42][4];      // 14,784 B
  float* const lds = &m_s[0][0][0];

  float acc0[49], acc1[49];
#pragma unroll
  for (int d = 0; d < 49; ++d) { acc0[d] = 0.f; acc1[d] = 0.f; }

  int goff0, goff1, goff2, goff3, loff0, loff1, loff2, loff3;
  float msk0, msk1, msk2, msk3;
#define K1_DECOMP(K, GO, LO, MS)                                           \
  {                                                                        \
    const int it = (tid + (K << 8)) < 836 ? (tid + (K << 8)) : 835;        \
    const int yy = it / 38;                                                \
    const int xx = it - 38 * yy;                                           \
    const int gy = h0 - 3 + yy, gx = w0 - 3 + xx;                          \
    MS = (((unsigned)gy < 128u) && ((unsigned)gx < 128u)) ? 1.f : 0.f;     \
    const int gyc = gy < 0 ? 0 : (gy > 127 ? 127 : gy);                    \
    const int gxc = gx < 0 ? 0 : (gx > 127 ? 127 : gx);                    \
    GO = (gyc << 7) + gxc;                                                 \
    LO = (yy * 42 + xx + 1) << 2;                                          \
  }
  K1_DECOMP(0, goff0, loff0, msk0)
  K1_DECOMP(1, goff1, loff1, msk1)
  K1_DECOMP(2, goff2, loff2, msk2)
  K1_DECOMP(3, goff3, loff3, msk3)
#undef K1_DECOMP
  const bool has3 = (tid < 68);

  const int qpix = ((h0 + 2 * ty) << 7) + w0 + tx;   // px0; px1 = +128

  float4 r0, r1, r2, r3;
  float qa[4], qb[4];
#define K1_LOAD(CC)                                                        \
  {                                                                        \
    const float* base = m_in + (((b * 64 + (CC) * 4) * 4 + t) << 14);      \
    const float* q;                                                        \
    q = base + goff0; r0.x = q[0]; r0.y = q[65536]; r0.z = q[131072]; r0.w = q[196608]; \
    q = base + goff1; r1.x = q[0]; r1.y = q[65536]; r1.z = q[131072]; r1.w = q[196608]; \
    q = base + goff2; r2.x = q[0]; r2.y = q[65536]; r2.z = q[131072]; r2.w = q[196608]; \
    if (has3) { q = base + goff3;                                          \
      r3.x = q[0]; r3.y = q[65536]; r3.z = q[131072]; r3.w = q[196608]; }  \
  }
  r3 = make_float4(0.f, 0.f, 0.f, 0.f);
  K1_LOAD(0)
#pragma unroll
  for (int k = 0; k < 4; ++k) {
    const float* qp = q_in + ((b * 64 + k) << 14) + qpix;
    qa[k] = qp[0];
    qb[k] = qp[128];
  }

#pragma unroll 1
  for (int cc = 0; cc < 16; ++cc) {     // 16 chunks x 4 channels
    __syncthreads();                    // prev phase's reads complete
    *(float4*)(lds + loff0) = make_float4(r0.x*msk0, r0.y*msk0, r0.z*msk0, r0.w*msk0);
    *(float4*)(lds + loff1) = make_float4(r1.x*msk1, r1.y*msk1, r1.z*msk1, r1.w*msk1);
    *(float4*)(lds + loff2) = make_float4(r2.x*msk2, r2.y*msk2, r2.z*msk2, r2.w*msk2);
    if (has3)
      *(float4*)(lds + loff3) = make_float4(r3.x*msk3, r3.y*msk3, r3.z*msk3, r3.w*msk3);
    __syncthreads();                    // writes visible

    float qan[4], qbn[4];
    if (cc < 15) {                      // issue next chunk's loads (no wait)
      K1_LOAD(cc + 1)
#pragma unroll
      for (int k = 0; k < 4; ++k) {
        const float* qp = q_in + ((b * 64 + (cc + 1) * 4 + k) << 14) + qpix;
        qan[k] = qp[0];
        qbn[k] = qp[128];
      }
    }

#pragma unroll
    for (int wr = 0; wr < 8; ++wr) {
      const float4* rowp = (const float4*)&m_s[2 * ty + wr][tx + 1][0];
#pragma unroll
      for (int dx = 0; dx < 7; ++dx) {
        const float4 mv = rowp[dx];
        if (wr < 7)
          acc0[wr * 7 + dx] += qa[0]*mv.x + qa[1]*mv.y + qa[2]*mv.z + qa[3]*mv.w;
        if (wr > 0)
          acc1[(wr - 1) * 7 + dx] += qb[0]*mv.x + qb[1]*mv.y + qb[2]*mv.z + qb[3]*mv.w;
      }
    }

    if (cc < 15) {
#pragma unroll
      for (int k = 0; k < 4; ++k) { qa[k] = qan[k]; qb[k] = qbn[k]; }
    }
  }
#undef K1_LOAD

  const int obase = ATTN_OFF + ((b * 196 + t) << 14)
                  + ((h0 + 2 * ty) << 7) + w0 + tx;
#pragma unroll
  for (int d = 0; d < 49; ++d) {
    out[obase +       ((d * 4) << 14)] = acc0[d];
    out[obase + 128 + ((d * 4) << 14)] = acc1[d];
  }
}

// ---------------------------------------------------------------------------
// K2 (FROZEN, near BW floor): softmax + packed-attn write into d_ws.
// Packed layout keyed to k3's wave tiling: G = (h>>1)*4 + (w>>5),
// lane = (h&1)*32 + (w&31); element (b,G,t,g,lane) at
// ((b*256+G)*4+t)*13*64 + g*64 + lane   (float4 units, d = 4g+j).
// ---------------------------------------------------------------------------
__global__ __launch_bounds__(256) void k2_softmax(
    float* __restrict__ out, const float* __restrict__ cst,
    float4* __restrict__ ws)
{
  const int tid = threadIdx.x;
  const int pl = tid & 63;             // pixel within block
  const int t  = tid >> 6;
  const int pix = blockIdx.x * 64 + pl;      // 65536 pixels total
  const int b = pix >> 14, hw = pix & 16383;
  float* base = out + ATTN_OFF + ((b * 196 + t) << 14) + hw;

  float v[49];
#pragma unroll
  for (int d = 0; d < 49; ++d) v[d] = base[(d * 4) << 14];

  float mx = -1e30f;
#pragma unroll
  for (int d = 0; d < 49; ++d) mx = fmaxf(mx, v[d]);

  __shared__ float red[4][64];
  red[t][pl] = mx;
  __syncthreads();
  float M = fmaxf(fmaxf(red[0][pl], red[1][pl]), fmaxf(red[2][pl], red[3][pl]));
  M = fmaxf(M, cst[0]);
  __syncthreads();

  float s = 0.f;
#pragma unroll
  for (int d = 0; d < 49; ++d) { v[d] = __expf(v[d] - M); s += v[d]; }
  red[t][pl] = s;
  __syncthreads();
  const float l = red[0][pl] + red[1][pl] + red[2][pl] + red[3][pl]
                + __expf(cst[0] - M);
  const float inv = 1.f / l;
#pragma unroll
  for (int d = 0; d < 49; ++d) {
    const float r = v[d] * inv;
    base[(d * 4) << 14] = r;           // reference-layout output (validated)
    v[d] = r;
  }

  if (ws) {
    const int h = hw >> 7, wc = hw & 127;
    const int G    = ((h >> 1) << 2) + (wc >> 5);
    const int lane = ((h & 1) << 5) + (wc & 31);
    float4* dst = ws + (size_t)(((b * 256 + G) * 4 + t) * 13) * 64 + lane;
#pragma unroll
    for (int g = 0; g < 13; ++g) {
      float4 p;
      p.x = v[g * 4];
      p.y = (g < 12) ? v[g * 4 + 1] : 0.f;
      p.z = (g < 12) ? v[g * 4 + 2] : 0.f;
      p.w = (g < 12) ? v[g * 4 + 3] : 0.f;
      dst[g * 64] = p;
    }
  }
}

// ---------------------------------------------------------------------------
// K3 v9 (packed-ws): 2-px window sharing + LAZY float4-group attn window.
//  - v8 skeleton (VGPR-bounded, validated) but attn restored to coalesced
//    float4 loads (v8's 98 scalar dwords/t at stride-16B quadrupled VMEM
//    instruction count and lost to v6). A row of 7 d's spans 2-3 packed
//    g-groups; per unrolled wr region we load only the NEW g's needed one
//    region ahead (<=2 f4 px0 + <=2 f4 px1, consecutive lanes -> coalesced).
//  - A0[13]/A1[13] statically indexed; per-region sched_barrier(0) keeps
//    the live window at 4-6 f4/px (v8-proven register discipline).
//  - FMA order identical to v8 -> numerics unchanged.
// ---------------------------------------------------------------------------
__global__ __launch_bounds__(256, 2) void k3_read_ws(
    const float* __restrict__ m_out, float* __restrict__ out,
    const float4* __restrict__ ws)
{
  // bijective XCD swizzle (2048 % 8 == 0), cq fastest within each XCD
  const int p = blockIdx.x + (blockIdx.y << 2) + (blockIdx.z << 5);
  const int l = ((p & 7) << 8) + (p >> 3);
  const int cq = l & 15;                     // 16 groups x 4 channels
  const int tile = l >> 4;                   // 0..127
  const int bx = tile & 3, by = (tile >> 2) & 7, b = tile >> 5;

  const int h0 = by * 16, w0 = bx * 32;
  const int tid = threadIdx.x;
  const int tx = tid & 31, ty = tid >> 5;    // px rows 2ty, 2ty+1
  const int G = ((h0 >> 1) + ty) * 4 + bx;   // shared by both pixels

  __shared__ float m_s[22][42][4];    // 14,784 B
  float* const lds = &m_s[0][0][0];

  float acc0[4], acc1[4];
#pragma unroll
  for (int i = 0; i < 4; ++i) { acc0[i] = 0.f; acc1[i] = 0.f; }

  int goff0, goff1, goff2, goff3, loff0, loff1, loff2, loff3;
  float msk0, msk1, msk2, msk3;
#define K3_DECOMP(K, GO, LO, MS)                                           \
  {                                                                        \
    const int it = (tid + (K << 8)) < 836 ? (tid + (K << 8)) : 835;        \
    const int yy = it / 38;                                                \
    const int xx = it - 38 * yy;                                           \
    const int gy = h0 - 3 + yy, gx = w0 - 3 + xx;                          \
    MS = (((unsigned)gy < 128u) && ((unsigned)gx < 128u)) ? 1.f : 0.f;     \
    const int gyc = gy < 0 ? 0 : (gy > 127 ? 127 : gy);                    \
    const int gxc = gx < 0 ? 0 : (gx > 127 ? 127 : gx);                    \
    GO = (gyc << 7) + gxc;                                                 \
    LO = (yy * 42 + xx + 1) << 2;                                          \
  }
  K3_DECOMP(0, goff0, loff0, msk0)
  K3_DECOMP(1, goff1, loff1, msk1)
  K3_DECOMP(2, goff2, loff2, msk2)
  K3_DECOMP(3, goff3, loff3, msk3)
#undef K3_DECOMP
  const bool has3 = (tid < 68);

  float4 r0, r1, r2, r3;
#define K3_LOAD(T)                                                         \
  {                                                                        \
    const float* base = m_out + (((b * 64 + cq * 4) * 4 + (T)) << 14);     \
    const float* q;                                                        \
    q = base + goff0; r0.x = q[0]; r0.y = q[65536]; r0.z = q[131072]; r0.w = q[196608]; \
    q = base + goff1; r1.x = q[0]; r1.y = q[65536]; r1.z = q[131072]; r1.w = q[196608]; \
    q = base + goff2; r2.x = q[0]; r2.y = q[65536]; r2.z = q[131072]; r2.w = q[196608]; \
    if (has3) { q = base + goff3;                                          \
      r3.x = q[0]; r3.y = q[65536]; r3.z = q[131072]; r3.w = q[196608]; }  \
  }
  r3 = make_float4(0.f, 0.f, 0.f, 0.f);
  K3_LOAD(0)

  // component select with static index
#define COMP(V, J) ((J) == 0 ? (V).x : (J) == 1 ? (V).y : (J) == 2 ? (V).z : (V).w)

#pragma unroll 1
  for (int t = 0; t < 4; ++t) {
    const float4* ap0 = ws + (size_t)(((b * 256 + G) * 4 + t) * 13) * 64 + tx;
    const float4* ap1 = ap0 + 32;

    float4 A0[13], A1[13];
    // preload px0 row 0 groups (g0,g1) — overlaps the barrier wait
    A0[0] = ap0[0];
    A0[1] = ap0[64];

    __syncthreads();                   // prev phase's reads complete
    *(float4*)(lds + loff0) = make_float4(r0.x*msk0, r0.y*msk0, r0.z*msk0, r0.w*msk0);
    *(float4*)(lds + loff1) = make_float4(r1.x*msk1, r1.y*msk1, r1.z*msk1, r1.w*msk1);
    *(float4*)(lds + loff2) = make_float4(r2.x*msk2, r2.y*msk2, r2.z*msk2, r2.w*msk2);
    if (has3)
      *(float4*)(lds + loff3) = make_float4(r3.x*msk3, r3.y*msk3, r3.z*msk3, r3.w*msk3);
    __syncthreads();                   // writes visible

    if (t < 3) K3_LOAD(t + 1)          // issue next t's m_out loads (no wait)

#pragma unroll
    for (int wr = 0; wr < 8; ++wr) {
      __builtin_amdgcn_sched_barrier(0);   // keep per-region loads local

      // lazy attn loads, one region ahead (px0 row wr+1; px1 row wr)
      if (wr == 0) { A0[2] = ap0[2*64];  A0[3] = ap0[3*64];
                     A1[0] = ap1[0];     A1[1] = ap1[64]; }
      if (wr == 1) { A0[4] = ap0[4*64];  A0[5] = ap0[5*64];
                     A1[2] = ap1[2*64];  A1[3] = ap1[3*64]; }
      if (wr == 2) { A0[6] = ap0[6*64];
                     A1[4] = ap1[4*64];  A1[5] = ap1[5*64]; }
      if (wr == 3) { A0[7] = ap0[7*64];  A0[8] = ap0[8*64];
                     A1[6] = ap1[6*64]; }
      if (wr == 4) { A0[9] = ap0[9*64];  A0[10] = ap0[10*64];
                     A1[7] = ap1[7*64];  A1[8] = ap1[8*64]; }
      if (wr == 5) { A0[11] = ap0[11*64]; A0[12] = ap0[12*64];
                     A1[9] = ap1[9*64];  A1[10] = ap1[10*64]; }
      if (wr == 6) { A1[11] = ap1[11*64]; A1[12] = ap1[12*64]; }

      const float4* rowp = (const float4*)&m_s[2 * ty + wr][tx + 1][0];
#pragma unroll
      for (int dx = 0; dx < 7; ++dx) {
        const float4 mv = rowp[dx];
        if (wr < 7) {
          const int d = wr * 7 + dx;
          const float a = COMP(A0[d >> 2], d & 3);
          acc0[0] += a * mv.x; acc0[1] += a * mv.y;
          acc0[2] += a * mv.z; acc0[3] += a * mv.w;
        }
        if (wr > 0) {
          const int d = (wr - 1) * 7 + dx;
          const float a = COMP(A1[d >> 2], d & 3);
          acc1[0] += a * mv.x; acc1[1] += a * mv.y;
          acc1[2] += a * mv.z; acc1[3] += a * mv.w;
        }
      }
    }
  }
#undef K3_LOAD
#undef COMP

  const int ob = ((b * 64 + cq * 4) << 14) + ((h0 + 2 * ty) << 7) + w0 + tx;
#pragma unroll
  for (int k = 0; k < 4; ++k) {
    out[ob +       (k << 14)] = acc0[k];
    out[ob + 128 + (k << 14)] = acc1[k];
  }
}

// ---------------------------------------------------------------------------
// K3 fallback (unchanged) — used only if ws_size is too small.
// ---------------------------------------------------------------------------
__global__ __launch_bounds__(256) void k3_read_fb(
    const float* __restrict__ m_out, float* __restrict__ out)
{
  const int b = blockIdx.z >> 2, cq = blockIdx.z & 3;
  const int h0 = blockIdx.y * 8, w0 = blockIdx.x * 32;
  const int tid = threadIdx.x;
  const int tx = tid & 31, ty = tid >> 5;
  const int h = h0 + ty, w = w0 + tx;

  __shared__ float m_s[4][14][38][4];
  const float* __restrict__ attn = out + ATTN_OFF;

  float acc[16];
#pragma unroll
  for (int i = 0; i < 16; ++i) acc[i] = 0.f;

#pragma unroll 1
  for (int t = 0; t < 4; ++t) {
    float a[49];
#pragma unroll
    for (int d = 0; d < 49; ++d)
      a[d] = attn[((b * 196 + d * 4 + t) << 14) + (h << 7) + w];

    __syncthreads();
    for (int e = tid; e < 8512; e += 256) {
      int c16 = e / 532; int rem = e - c16 * 532;
      int y = rem / 38;  int x = rem - y * 38;
      int gy = h0 - 3 + y, gx = w0 - 3 + x;
      float v = 0.f;
      if (gy >= 0 && gy < 128 && gx >= 0 && gx < 128)
        v = m_out[(((b * 64 + cq * 16 + c16) * 4 + t) << 14) + (gy << 7) + gx];
      m_s[c16 >> 2][y][x][c16 & 3] = v;
    }
    __syncthreads();

#pragma unroll
    for (int dy = 0; dy < 7; ++dy)
#pragma unroll
      for (int dx = 0; dx < 7; ++dx) {
        const float av = a[dy * 7 + dx];
#pragma unroll
        for (int q = 0; q < 4; ++q) {
          const float4 mv = *(const float4*)&m_s[q][ty + dy][tx + dx][0];
          acc[q * 4 + 0] += av * mv.x;
          acc[q * 4 + 1] += av * mv.y;
          acc[q * 4 + 2] += av * mv.z;
          acc[q * 4 + 3] += av * mv.w;
        }
      }
  }

#pragma unroll
  for (int q = 0; q < 4; ++q)
#pragma unroll
    for (int k = 0; k < 4; ++k)
      out[((b * 64 + cq * 16 + q * 4 + k) << 14) + (h << 7) + w] = acc[q * 4 + k];
}

extern "C" void kernel_launch(void* const* d_in, const int* in_sizes, int n_in,
                              void* d_out, int out_size, void* d_ws, size_t ws_size,
                              hipStream_t stream) {
  const float* m_in  = (const float*)d_in[0];
  const float* m_out = (const float*)d_in[1];
  const float* q_in  = (const float*)d_in[2];
  const float* cst   = (const float*)d_in[3];
  float* out = (float*)d_out;

  const bool use_ws = (ws_size >= WS_F4_COUNT * 16ull) && d_ws != nullptr;
  float4* ws = use_ws ? (float4*)d_ws : nullptr;

  k1_corr<<<dim3(4, 8, 16), dim3(256), 0, stream>>>(m_in, q_in, out);
  k2_softmax<<<dim3(1024), dim3(256), 0, stream>>>(out, cst, ws);
  if (use_ws)
    k3_read_ws<<<dim3(4, 8, 64), dim3(256), 0, stream>>>(m_out, out, ws);
  else
    k3_read_fb<<<dim3(4, 16, 16), dim3(256), 0, stream>>>(m_out, out);
}

// Round 18
// 123.987 us; speedup vs baseline: 1.3145x; 1.0112x over previous
//
#include <hip/hip_runtime.h>

// Problem constants: B=4, De=Do=64, T=4, H=W=128, PATCH=7, R=3
#define ATTN_OFF 4194304                 // B*Do*H*W (mem region size in floats)
// packed attn ws: [b][G=256][t][13][64] float4  = 3,407,872 float4s
#define WS_F4_COUNT 3407872ull

// ---------------------------------------------------------------------------
// K1 v12 (FROZEN, wall-validated R14): 2-px window sharing, conflict-free
// b128 staging, XCD swizzle, early-issue/write-late pipeline + q prefetch.
// ---------------------------------------------------------------------------
__global__ __launch_bounds__(256, 1) void k1_corr(
    const float* __restrict__ m_in, const float* __restrict__ q_in,
    float* __restrict__ out)
{
  // bijective XCD swizzle (512 % 8 == 0)
  const int p = blockIdx.x + (blockIdx.y << 2) + (blockIdx.z << 5);
  const int l = ((p & 7) << 6) + (p >> 3);
  const int bx = l & 3, by = (l >> 2) & 7, bz = l >> 5;

  const int b = bz >> 2, t = bz & 3;
  const int h0 = by * 16, w0 = bx * 32;
  const int tid = threadIdx.x;
  const int tx = tid & 31, ty = tid >> 5;      // ty 0..7 -> px rows 2ty, 2ty+1

  __shared__ float m_s[22][42][4];      // 14,784 B
  float* const lds = &m_s[0][0][0];

  float acc0[49], acc1[49];
#pragma unroll
  for (int d = 0; d < 49; ++d) { acc0[d] = 0.f; acc1[d] = 0.f; }

  int goff0, goff1, goff2, goff3, loff0, loff1, loff2, loff3;
  float msk0, msk1, msk2, msk3;
#define K1_DECOMP(K, GO, LO, MS)                                           \
  {                                                                        \
    const int it = (tid + (K << 8)) < 836 ? (tid + (K << 8)) : 835;        \
    const int yy = it / 38;                                                \
    const int xx = it - 38 * yy;                                           \
    const int gy = h0 - 3 + yy, gx = w0 - 3 + xx;                          \
    MS = (((unsigned)gy < 128u) && ((unsigned)gx < 128u)) ? 1.f : 0.f;     \
    const int gyc = gy < 0 ? 0 : (gy > 127 ? 127 : gy);                    \
    const int gxc = gx < 0 ? 0 : (gx > 127 ? 127 : gx);                    \
    GO = (gyc << 7) + gxc;                                                 \
    LO = (yy * 42 + xx + 1) << 2;                                          \
  }
  K1_DECOMP(0, goff0, loff0, msk0)
  K1_DECOMP(1, goff1, loff1, msk1)
  K1_DECOMP(2, goff2, loff2, msk2)
  K1_DECOMP(3, goff3, loff3, msk3)
#undef K1_DECOMP
  const bool has3 = (tid < 68);

  const int qpix = ((h0 + 2 * ty) << 7) + w0 + tx;   // px0; px1 = +128

  float4 r0, r1, r2, r3;
  float qa[4], qb[4];
#define K1_LOAD(CC)                                                        \
  {                                                                        \
    const float* base = m_in + (((b * 64 + (CC) * 4) * 4 + t) << 14);      \
    const float* q;                                                        \
    q = base + goff0; r0.x = q[0]; r0.y = q[65536]; r0.z = q[131072]; r0.w = q[196608]; \
    q = base + goff1; r1.x = q[0]; r1.y = q[65536]; r1.z = q[131072]; r1.w = q[196608]; \
    q = base + goff2; r2.x = q[0]; r2.y = q[65536]; r2.z = q[131072]; r2.w = q[196608]; \
    if (has3) { q = base + goff3;                                          \
      r3.x = q[0]; r3.y = q[65536]; r3.z = q[131072]; r3.w = q[196608]; }  \
  }
  r3 = make_float4(0.f, 0.f, 0.f, 0.f);
  K1_LOAD(0)
#pragma unroll
  for (int k = 0; k < 4; ++k) {
    const float* qp = q_in + ((b * 64 + k) << 14) + qpix;
    qa[k] = qp[0];
    qb[k] = qp[128];
  }

#pragma unroll 1
  for (int cc = 0; cc < 16; ++cc) {     // 16 chunks x 4 channels
    __syncthreads();                    // prev phase's reads complete
    *(float4*)(lds + loff0) = make_float4(r0.x*msk0, r0.y*msk0, r0.z*msk0, r0.w*msk0);
    *(float4*)(lds + loff1) = make_float4(r1.x*msk1, r1.y*msk1, r1.z*msk1, r1.w*msk1);
    *(float4*)(lds + loff2) = make_float4(r2.x*msk2, r2.y*msk2, r2.z*msk2, r2.w*msk2);
    if (has3)
      *(float4*)(lds + loff3) = make_float4(r3.x*msk3, r3.y*msk3, r3.z*msk3, r3.w*msk3);
    __syncthreads();                    // writes visible

    float qan[4], qbn[4];
    if (cc < 15) {                      // issue next chunk's loads (no wait)
      K1_LOAD(cc + 1)
#pragma unroll
      for (int k = 0; k < 4; ++k) {
        const float* qp = q_in + ((b * 64 + (cc + 1) * 4 + k) << 14) + qpix;
        qan[k] = qp[0];
        qbn[k] = qp[128];
      }
    }

#pragma unroll
    for (int wr = 0; wr < 8; ++wr) {
      const float4* rowp = (const float4*)&m_s[2 * ty + wr][tx + 1][0];
#pragma unroll
      for (int dx = 0; dx < 7; ++dx) {
        const float4 mv = rowp[dx];
        if (wr < 7)
          acc0[wr * 7 + dx] += qa[0]*mv.x + qa[1]*mv.y + qa[2]*mv.z + qa[3]*mv.w;
        if (wr > 0)
          acc1[(wr - 1) * 7 + dx] += qb[0]*mv.x + qb[1]*mv.y + qb[2]*mv.z + qb[3]*mv.w;
      }
    }

    if (cc < 15) {
#pragma unroll
      for (int k = 0; k < 4; ++k) { qa[k] = qan[k]; qb[k] = qbn[k]; }
    }
  }
#undef K1_LOAD

  const int obase = ATTN_OFF + ((b * 196 + t) << 14)
                  + ((h0 + 2 * ty) << 7) + w0 + tx;
#pragma unroll
  for (int d = 0; d < 49; ++d) {
    out[obase +       ((d * 4) << 14)] = acc0[d];
    out[obase + 128 + ((d * 4) << 14)] = acc1[d];
  }
}

// ---------------------------------------------------------------------------
// K2 (FROZEN, near BW floor): softmax + packed-attn write into d_ws.
// Packed layout keyed to k3's wave tiling: G = (h>>1)*4 + (w>>5),
// lane = (h&1)*32 + (w&31); element (b,G,t,g,lane) at
// ((b*256+G)*4+t)*13*64 + g*64 + lane   (float4 units, d = 4g+j).
// ---------------------------------------------------------------------------
__global__ __launch_bounds__(256) void k2_softmax(
    float* __restrict__ out, const float* __restrict__ cst,
    float4* __restrict__ ws)
{
  const int tid = threadIdx.x;
  const int pl = tid & 63;             // pixel within block
  const int t  = tid >> 6;
  const int pix = blockIdx.x * 64 + pl;      // 65536 pixels total
  const int b = pix >> 14, hw = pix & 16383;
  float* base = out + ATTN_OFF + ((b * 196 + t) << 14) + hw;

  float v[49];
#pragma unroll
  for (int d = 0; d < 49; ++d) v[d] = base[(d * 4) << 14];

  float mx = -1e30f;
#pragma unroll
  for (int d = 0; d < 49; ++d) mx = fmaxf(mx, v[d]);

  __shared__ float red[4][64];
  red[t][pl] = mx;
  __syncthreads();
  float M = fmaxf(fmaxf(red[0][pl], red[1][pl]), fmaxf(red[2][pl], red[3][pl]));
  M = fmaxf(M, cst[0]);
  __syncthreads();

  float s = 0.f;
#pragma unroll
  for (int d = 0; d < 49; ++d) { v[d] = __expf(v[d] - M); s += v[d]; }
  red[t][pl] = s;
  __syncthreads();
  const float l = red[0][pl] + red[1][pl] + red[2][pl] + red[3][pl]
                + __expf(cst[0] - M);
  const float inv = 1.f / l;
#pragma unroll
  for (int d = 0; d < 49; ++d) {
    const float r = v[d] * inv;
    base[(d * 4) << 14] = r;           // reference-layout output (validated)
    v[d] = r;
  }

  if (ws) {
    const int h = hw >> 7, wc = hw & 127;
    const int G    = ((h >> 1) << 2) + (wc >> 5);
    const int lane = ((h & 1) << 5) + (wc & 31);
    float4* dst = ws + (size_t)(((b * 256 + G) * 4 + t) * 13) * 64 + lane;
#pragma unroll
    for (int g = 0; g < 13; ++g) {
      float4 p;
      p.x = v[g * 4];
      p.y = (g < 12) ? v[g * 4 + 1] : 0.f;
      p.z = (g < 12) ? v[g * 4 + 2] : 0.f;
      p.w = (g < 12) ? v[g * 4 + 3] : 0.f;
      dst[g * 64] = p;
    }
  }
}

// ---------------------------------------------------------------------------
// K3 v6 (RESTORED — R14 champion config): cq-fastest XCD swizzle +
// early-issue staging, 8-channel blocks, conflict-free staging,
// g-pipelined coalesced ws reads. 1 px/thread.
// (2-px variants v7/v8/v9 all lost: attn delivery cost > LDS savings.)
// ---------------------------------------------------------------------------
__global__ __launch_bounds__(256) void k3_read_ws(
    const float* __restrict__ m_out, float* __restrict__ out,
    const float4* __restrict__ ws)
{
  // bijective XCD swizzle (2048 % 8 == 0), cq fastest within each XCD
  const int p = blockIdx.x + (blockIdx.y << 2) + (blockIdx.z << 6);
  const int l = ((p & 7) << 8) + (p >> 3);
  const int cq = l & 7;
  const int tile = l >> 3;
  const int bx = tile & 3, by = (tile >> 2) & 15, b = tile >> 6;

  const int h0 = by * 8, w0 = bx * 32;
  const int tid = threadIdx.x;
  const int tx = tid & 31, ty = tid >> 5;
  const int h = h0 + ty, w = w0 + tx;
  const int waveid = tid >> 6, lane = tid & 63;
  const int G = ((h0 >> 1) + waveid) * 4 + bx;

  __shared__ float m_s[2][14][42][4];  // 18,816 B
  float* const lds = &m_s[0][0][0][0];

  float acc[8];
#pragma unroll
  for (int i = 0; i < 8; ++i) acc[i] = 0.f;

  int goff0, goff1, goff2, goff3, goff4;
  int loff0, loff1, loff2, loff3, loff4;
  float msk0, msk1, msk2, msk3, msk4;
#define K3_DECOMP(K, GO, LO, MS)                                           \
  {                                                                        \
    const int it  = (tid + (K << 8)) < 1064 ? (tid + (K << 8)) : 1063;     \
    const int qd  = it >= 532;                                             \
    const int rem = it - 532 * qd;                                         \
    const int yy  = rem / 38;                                              \
    const int xx  = rem - 38 * yy;                                         \
    const int gy  = h0 - 3 + yy, gx = w0 - 3 + xx;                         \
    MS = (((unsigned)gy < 128u) && ((unsigned)gx < 128u)) ? 1.f : 0.f;     \
    const int gyc = gy < 0 ? 0 : (gy > 127 ? 127 : gy);                    \
    const int gxc = gx < 0 ? 0 : (gx > 127 ? 127 : gx);                    \
    GO = (qd << 18) + (gyc << 7) + gxc;                                    \
    LO = (((qd * 14 + yy) * 42) + xx + 1) << 2;                            \
  }
  K3_DECOMP(0, goff0, loff0, msk0)
  K3_DECOMP(1, goff1, loff1, msk1)
  K3_DECOMP(2, goff2, loff2, msk2)
  K3_DECOMP(3, goff3, loff3, msk3)
  K3_DECOMP(4, goff4, loff4, msk4)
#undef K3_DECOMP
  const bool has4 = (tid < 40);

  float4 r0, r1, r2, r3, r4;
#define K3_LOAD(T)                                                         \
  {                                                                        \
    const float* base = m_out + (((b * 64 + cq * 8) * 4 + (T)) << 14);     \
    const float* q;                                                        \
    q = base + goff0; r0.x = q[0]; r0.y = q[65536]; r0.z = q[131072]; r0.w = q[196608]; \
    q = base + goff1; r1.x = q[0]; r1.y = q[65536]; r1.z = q[131072]; r1.w = q[196608]; \
    q = base + goff2; r2.x = q[0]; r2.y = q[65536]; r2.z = q[131072]; r2.w = q[196608]; \
    q = base + goff3; r3.x = q[0]; r3.y = q[65536]; r3.z = q[131072]; r3.w = q[196608]; \
    if (has4) { q = base + goff4;                                          \
      r4.x = q[0]; r4.y = q[65536]; r4.z = q[131072]; r4.w = q[196608]; }  \
  }
  r4 = make_float4(0.f, 0.f, 0.f, 0.f);
  K3_LOAD(0)

#pragma unroll 1
  for (int t = 0; t < 4; ++t) {
    const float4* ap = ws + (size_t)(((b * 256 + G) * 4 + t) * 13) * 64 + lane;

    __syncthreads();                   // prev phase's reads complete
    *(float4*)(lds + loff0) = make_float4(r0.x*msk0, r0.y*msk0, r0.z*msk0, r0.w*msk0);
    *(float4*)(lds + loff1) = make_float4(r1.x*msk1, r1.y*msk1, r1.z*msk1, r1.w*msk1);
    *(float4*)(lds + loff2) = make_float4(r2.x*msk2, r2.y*msk2, r2.z*msk2, r2.w*msk2);
    *(float4*)(lds + loff3) = make_float4(r3.x*msk3, r3.y*msk3, r3.z*msk3, r3.w*msk3);
    if (has4)
      *(float4*)(lds + loff4) = make_float4(r4.x*msk4, r4.y*msk4, r4.z*msk4, r4.w*msk4);
    __syncthreads();                   // writes visible

    if (t < 3) K3_LOAD(t + 1)          // issue next t's loads (no wait)

    float4 cur = ap[0];
#pragma unroll
    for (int g = 0; g < 13; ++g) {
      float4 nxt = cur;
      if (g < 12) nxt = ap[(g + 1) * 64];
#pragma unroll
      for (int j = 0; j < 4; ++j) {
        const int d = g * 4 + j;
        if (d >= 49) break;
        const int dy = d / 7, dx = d % 7;
        const float av = (j == 0) ? cur.x : (j == 1) ? cur.y
                       : (j == 2) ? cur.z : cur.w;
#pragma unroll
        for (int q = 0; q < 2; ++q) {
          const float4 mv = *(const float4*)&m_s[q][ty + dy][tx + dx + 1][0];
          acc[q * 4 + 0] += av * mv.x;
          acc[q * 4 + 1] += av * mv.y;
          acc[q * 4 + 2] += av * mv.z;
          acc[q * 4 + 3] += av * mv.w;
        }
      }
      cur = nxt;
    }
  }
#undef K3_LOAD

#pragma unroll
  for (int q = 0; q < 2; ++q)
#pragma unroll
    for (int k = 0; k < 4; ++k)
      out[((b * 64 + cq * 8 + q * 4 + k) << 14) + (h << 7) + w] = acc[q * 4 + k];
}

// ---------------------------------------------------------------------------
// K3 fallback (unchanged) — used only if ws_size is too small.
// ---------------------------------------------------------------------------
__global__ __launch_bounds__(256) void k3_read_fb(
    const float* __restrict__ m_out, float* __restrict__ out)
{
  const int b = blockIdx.z >> 2, cq = blockIdx.z & 3;
  const int h0 = blockIdx.y * 8, w0 = blockIdx.x * 32;
  const int tid = threadIdx.x;
  const int tx = tid & 31, ty = tid >> 5;
  const int h = h0 + ty, w = w0 + tx;

  __shared__ float m_s[4][14][38][4];
  const float* __restrict__ attn = out + ATTN_OFF;

  float acc[16];
#pragma unroll
  for (int i = 0; i < 16; ++i) acc[i] = 0.f;

#pragma unroll 1
  for (int t = 0; t < 4; ++t) {
    float a[49];
#pragma unroll
    for (int d = 0; d < 49; ++d)
      a[d] = attn[((b * 196 + d * 4 + t) << 14) + (h << 7) + w];

    __syncthreads();
    for (int e = tid; e < 8512; e += 256) {
      int c16 = e / 532; int rem = e - c16 * 532;
      int y = rem / 38;  int x = rem - y * 38;
      int gy = h0 - 3 + y, gx = w0 - 3 + x;
      float v = 0.f;
      if (gy >= 0 && gy < 128 && gx >= 0 && gx < 128)
        v = m_out[(((b * 64 + cq * 16 + c16) * 4 + t) << 14) + (gy << 7) + gx];
      m_s[c16 >> 2][y][x][c16 & 3] = v;
    }
    __syncthreads();

#pragma unroll
    for (int dy = 0; dy < 7; ++dy)
#pragma unroll
      for (int dx = 0; dx < 7; ++dx) {
        const float av = a[dy * 7 + dx];
#pragma unroll
        for (int q = 0; q < 4; ++q) {
          const float4 mv = *(const float4*)&m_s[q][ty + dy][tx + dx][0];
          acc[q * 4 + 0] += av * mv.x;
          acc[q * 4 + 1] += av * mv.y;
          acc[q * 4 + 2] += av * mv.z;
          acc[q * 4 + 3] += av * mv.w;
        }
      }
  }

#pragma unroll
  for (int q = 0; q < 4; ++q)
#pragma unroll
    for (int k = 0; k < 4; ++k)
      out[((b * 64 + cq * 16 + q * 4 + k) << 14) + (h << 7) + w] = acc[q * 4 + k];
}

extern "C" void kernel_launch(void* const* d_in, const int* in_sizes, int n_in,
                              void* d_out, int out_size, void* d_ws, size_t ws_size,
                              hipStream_t stream) {
  const float* m_in  = (const float*)d_in[0];
  const float* m_out = (const float*)d_in[1];
  const float* q_in  = (const float*)d_in[2];
  const float* cst   = (const float*)d_in[3];
  float* out = (float*)d_out;

  const bool use_ws = (ws_size >= WS_F4_COUNT * 16ull) && d_ws != nullptr;
  float4* ws = use_ws ? (float4*)d_ws : nullptr;

  k1_corr<<<dim3(4, 8, 16), dim3(256), 0, stream>>>(m_in, q_in, out);
  k2_softmax<<<dim3(1024), dim3(256), 0, stream>>>(out, cst, ws);
  if (use_ws)
    k3_read_ws<<<dim3(4, 16, 32), dim3(256), 0, stream>>>(m_out, out, ws);
  else
    k3_read_fb<<<dim3(4, 16, 16), dim3(256), 0, stream>>>(m_out, out);
}